// Round 1
// baseline (318.907 us; speedup 1.0000x reference)
//
#include <hip/hip_runtime.h>

typedef unsigned short u16;
typedef unsigned int   u32;
typedef __attribute__((ext_vector_type(4))) short s4;
typedef __attribute__((ext_vector_type(8))) short s8;
typedef __attribute__((ext_vector_type(4))) float f4;

#define NB   8
#define SEQ  1025
#define DIM  768
#define NH   12
#define HD   64
#define MPAD 8320      // 65*128 padded rows of B*SEQ=8200
#define SQP  1040      // Q rows padded per (b,h): 65*16
#define SKP  1056      // K rows padded per (b,h): 33*32
#define NQKV 2304
#define BHT  96        // B*H

__device__ __forceinline__ u16 f2bf(float f) {
  u32 u = __builtin_bit_cast(u32, f);
  u += 0x7fffu + ((u >> 16) & 1u);
  return (u16)(u >> 16);
}
__device__ __forceinline__ float bf2f(u16 h) {
  return __builtin_bit_cast(float, ((u32)h) << 16);
}

typedef const __attribute__((address_space(1))) void cas1v;
typedef __attribute__((address_space(3))) void as3v;
__device__ __forceinline__ void gload16(const void* g, void* l) {
  __builtin_amdgcn_global_load_lds((cas1v*)g, (as3v*)l, 16, 0, 0);
}

#define MFMA16(a, b, c) __builtin_amdgcn_mfma_f32_16x16x32_bf16(a, b, c, 0, 0, 0)

// ---------------- convert x (f32 -> bf16, zero-pad rows >= 8200) ----------------
__global__ void conv_x(const float* __restrict__ x, u16* __restrict__ xb) {
  int i = blockIdx.x * 256 + threadIdx.x;      // 1,597,440 threads
  int e = i * 4;
  int row = e / DIM;
  s4 o;
  if (row < NB * SEQ) {
    float4 v = *(const float4*)(x + e);
    o[0] = (short)f2bf(v.x); o[1] = (short)f2bf(v.y);
    o[2] = (short)f2bf(v.z); o[3] = (short)f2bf(v.w);
  } else {
    o = (s4){0, 0, 0, 0};
  }
  *(s4*)(xb + e) = o;
}

// ---------------- convert weights + build fused qkv bias ----------------
__global__ void conv_w(const float* __restrict__ qw, const float* __restrict__ kw,
                       const float* __restrict__ vw, const float* __restrict__ ow,
                       const float* __restrict__ qb, const float* __restrict__ vb,
                       u16* __restrict__ wqkv, u16* __restrict__ wo, float* __restrict__ biasq) {
  int i = blockIdx.x * 256 + threadIdx.x;      // 589,824 threads
  wqkv[i]           = f2bf(qw[i]);
  wqkv[i + 589824]  = f2bf(kw[i]);
  wqkv[i + 1179648] = f2bf(vw[i]);
  wo[i]             = f2bf(ow[i]);
  if (i < NQKV) biasq[i] = (i < 768) ? qb[i] : (i < 1536 ? 0.f : vb[i - 1536]);
}

// ---------------- bf16 GEMM: C[m][n] = sum_k A[m][k]*B[n][k] + bias[n] ----------------
// m97 structure: 128x128 tile, BK=32, 4 waves (2x2), global_load_lds width 16.
template <int OUTF32>
__global__ __launch_bounds__(256) void gemm_bt(const u16* __restrict__ A, const u16* __restrict__ Bm,
                                               u16* __restrict__ Cb, float* __restrict__ Cf,
                                               const float* __restrict__ bias,
                                               int N, int K, int Mvalid) {
  __shared__ u16 As[128 * 32];
  __shared__ u16 Bs[128 * 32];
  int tid = threadIdx.x;
  int lane = tid & 63, wave = tid >> 6;
  int g = lane >> 4, c16 = lane & 15;
  int m0 = blockIdx.x * 128, n0 = blockIdx.y * 128;
  int wm = wave >> 1, wn = wave & 1;
  f4 acc[4][4] = {};

  int ldrow = wave * 16 + (lane >> 2);
  int ldk = (lane & 3) * 8;
  const u16* Asrc = A + (size_t)(m0 + ldrow) * K + ldk;
  const u16* Bsrc = Bm + (size_t)(n0 + ldrow) * K + ldk;
  u16* AsW = As + wave * 512;
  u16* BsW = Bs + wave * 512;

  for (int k0 = 0; k0 < K; k0 += 32) {
    __syncthreads();
    gload16(Asrc + k0,          AsW);
    gload16(Asrc + 64 * K + k0, AsW + 2048);
    gload16(Bsrc + k0,          BsW);
    gload16(Bsrc + 64 * K + k0, BsW + 2048);
    __syncthreads();
    s8 af[4], bf[4];
#pragma unroll
    for (int i = 0; i < 4; i++) {
      af[i] = *(const s8*)(As + (wm * 64 + i * 16 + c16) * 32 + g * 8);
      bf[i] = *(const s8*)(Bs + (wn * 64 + i * 16 + c16) * 32 + g * 8);
    }
#pragma unroll
    for (int i = 0; i < 4; i++)
#pragma unroll
      for (int j = 0; j < 4; j++)
        acc[i][j] = MFMA16(af[i], bf[j], acc[i][j]);
  }

#pragma unroll
  for (int i = 0; i < 4; i++)
#pragma unroll
    for (int j = 0; j < 4; j++) {
      int m = m0 + wm * 64 + i * 16 + g * 4;
      int n = n0 + wn * 64 + j * 16 + c16;
      float bv = bias ? bias[n] : 0.f;
#pragma unroll
      for (int r = 0; r < 4; r++) {
        if (m + r < Mvalid) {
          float v = acc[i][j][r] + bv;
          if (OUTF32) Cf[(size_t)(m + r) * N + n] = v;
          else        Cb[(size_t)(m + r) * N + n] = f2bf(v);
        }
      }
    }
}

// ---------------- RoPE for Q,K + relayout to padded per-(b,h) buffers ----------------
__global__ void rope_qk(const u16* __restrict__ qkv, u16* __restrict__ Ql, u16* __restrict__ Kl) {
  int t = blockIdx.x * 256 + threadIdx.x;        // 96*1056*32 threads
  int j = t & 31;
  int rem = t >> 5;
  int s = rem % SKP;
  int bh = rem / SKP;
  if (bh >= BHT) return;
  int b = bh / NH, h = bh % NH;
  size_t qoff = ((size_t)(bh * SQP + s)) * HD + 2 * j;
  size_t koff = ((size_t)(bh * SKP + s)) * HD + 2 * j;
  if (s >= SEQ) {
    *(u32*)(Kl + koff) = 0;
    if (s < SQP) *(u32*)(Ql + qoff) = 0;
    return;
  }
  size_t rowoff = ((size_t)(b * SEQ + s)) * NQKV + h * HD + 2 * j;
  u32 qp = *(const u32*)(qkv + rowoff);
  u32 kp = *(const u32*)(qkv + rowoff + DIM);
  float q0 = bf2f((u16)qp), q1 = bf2f((u16)(qp >> 16));
  float k0 = bf2f((u16)kp), k1 = bf2f((u16)(kp >> 16));
  float cs = 1.f, sn = 0.f;
  if (s > 0) {                                   // num_prefix_tokens = 1
    int tok = s - 1;
    int pos = (j < 16) ? (tok >> 5) : (tok & 31);
    int f = j & 15;
    float ang = (float)pos * __expf((float)f * -0.28782313662425572f); // 100^(-f/16)
    __sincosf(ang, &sn, &cs);
  }
  float q0r = q0 * cs - q1 * sn, q1r = q1 * cs + q0 * sn;
  float k0r = k0 * cs - k1 * sn, k1r = k1 * cs + k0 * sn;
  // fold scale hd^-0.5 = 0.125 into Q
  *(u32*)(Ql + qoff) = (u32)f2bf(q0r * 0.125f) | ((u32)f2bf(q1r * 0.125f) << 16);
  *(u32*)(Kl + koff) = (u32)f2bf(k0r) | ((u32)f2bf(k1r) << 16);
}

// ---------------- V transpose: qkv[.,1536+h*64+d] -> Vt[(bh*64+d)*SKP + s] ----------------
__global__ void v_trans(const u16* __restrict__ qkv, u16* __restrict__ Vt) {
  __shared__ u16 tile[32][72];
  int bh = blockIdx.x / 33, st = blockIdx.x % 33;
  int b = bh / NH, h = bh % NH;
  int s0 = st * 32;
  int tid = threadIdx.x;
  {
    int sl = tid >> 3, c8 = (tid & 7) * 8;
    int s = s0 + sl;
    s8 v = (s8){0, 0, 0, 0, 0, 0, 0, 0};
    if (s < SEQ) v = *(const s8*)(qkv + ((size_t)(b * SEQ + s)) * NQKV + 1536 + h * HD + c8);
    *(s8*)&tile[sl][c8] = v;
  }
  __syncthreads();
  {
    int d = tid >> 2, sc = (tid & 3) * 8;
    s8 o;
#pragma unroll
    for (int u = 0; u < 8; u++) o[u] = (short)tile[sc + u][d];
    *(s8*)(Vt + ((size_t)(bh * HD + d)) * SKP + s0 + sc) = o;
  }
}

// ---------------- flash attention, 1 wave = 16 q rows, swapped QK^T ----------------
__global__ __launch_bounds__(256) void attn_k(const u16* __restrict__ Q, const u16* __restrict__ K,
                                              const u16* __restrict__ V, u16* __restrict__ Ao) {
  int bh = blockIdx.x;
  int wave = threadIdx.x >> 6, lane = threadIdx.x & 63;
  int qb = blockIdx.y * 64 + wave * 16;
  if (qb >= SEQ) return;
  int g = lane >> 4, c16 = lane & 15;
  int b = bh / NH, h = bh % NH;
  const u16* Qb = Q + (size_t)bh * SQP * HD;
  const u16* Kb = K + (size_t)bh * SKP * HD;
  const u16* Vb = V + (size_t)bh * HD * SKP;

  s8 qf[2];
  qf[0] = *(const s8*)(Qb + (size_t)(qb + c16) * HD + g * 8);
  qf[1] = *(const s8*)(Qb + (size_t)(qb + c16) * HD + 32 + g * 8);

  f4 oacc[4] = {};
  float mrun = -1e30f, lrun = 0.f;

  for (int kv0 = 0; kv0 < SKP; kv0 += 32) {
    // St = K * Q^T : lane holds St[kk=(g*4+r)][q=c16]
    f4 st0 = {0.f, 0.f, 0.f, 0.f}, st1 = {0.f, 0.f, 0.f, 0.f};
    {
      const u16* kr0 = Kb + (size_t)(kv0 + c16) * HD;
      const u16* kr1 = Kb + (size_t)(kv0 + 16 + c16) * HD;
      s8 kf;
      kf = *(const s8*)(kr0 + g * 8);      st0 = MFMA16(kf, qf[0], st0);
      kf = *(const s8*)(kr0 + 32 + g * 8); st0 = MFMA16(kf, qf[1], st0);
      kf = *(const s8*)(kr1 + g * 8);      st1 = MFMA16(kf, qf[0], st1);
      kf = *(const s8*)(kr1 + 32 + g * 8); st1 = MFMA16(kf, qf[1], st1);
    }
    float sv[8];
    float smax = -1e30f;
#pragma unroll
    for (int r = 0; r < 4; r++) {
      int kk0 = kv0 + g * 4 + r;
      int kk1 = kv0 + 16 + g * 4 + r;
      sv[r]     = (kk0 < SEQ) ? st0[r] : -1e30f;
      sv[4 + r] = (kk1 < SEQ) ? st1[r] : -1e30f;
      smax = fmaxf(smax, fmaxf(sv[r], sv[4 + r]));
    }
    smax = fmaxf(smax, __shfl_xor(smax, 16));
    smax = fmaxf(smax, __shfl_xor(smax, 32));
    float mnew = fmaxf(mrun, smax);
    float cfac = __expf(mrun - mnew);
    float psum = 0.f;
    s8 pa;
#pragma unroll
    for (int i = 0; i < 8; i++) {
      float p = __expf(sv[i] - mnew);
      psum += p;
      pa[i] = (short)f2bf(p);
    }
    psum += __shfl_xor(psum, 16);
    psum += __shfl_xor(psum, 32);
    lrun = lrun * cfac + psum;
    mrun = mnew;

    float cf4[4];
#pragma unroll
    for (int r = 0; r < 4; r++) cf4[r] = __shfl(cfac, (lane & 48) | (g * 4 + r));

#pragma unroll
    for (int t = 0; t < 4; t++) {
      const u16* vr = Vb + (size_t)(t * 16 + c16) * SKP + kv0;
      s4 lo = *(const s4*)(vr + 4 * g);        // k = 4g + [0,4)
      s4 hi = *(const s4*)(vr + 16 + 4 * g);   // k = 16 + 4g + [0,4)
      s8 vf = (s8){lo[0], lo[1], lo[2], lo[3], hi[0], hi[1], hi[2], hi[3]};
      f4 o = oacc[t];
#pragma unroll
      for (int r = 0; r < 4; r++) o[r] *= cf4[r];
      oacc[t] = MFMA16(pa, vf, o);
    }
  }

  float lf4[4];
#pragma unroll
  for (int r = 0; r < 4; r++) lf4[r] = __shfl(lrun, (lane & 48) | (g * 4 + r));
#pragma unroll
  for (int t = 0; t < 4; t++)
#pragma unroll
    for (int r = 0; r < 4; r++) {
      int q = qb + g * 4 + r;
      if (q < SEQ) {
        float v = oacc[t][r] / lf4[r];
        Ao[((size_t)(b * SEQ + q)) * DIM + h * HD + t * 16 + c16] = f2bf(v);
      }
    }
}

extern "C" void kernel_launch(void* const* d_in, const int* in_sizes, int n_in,
                              void* d_out, int out_size, void* d_ws, size_t ws_size,
                              hipStream_t stream) {
  const float* x  = (const float*)d_in[0];
  const float* qw = (const float*)d_in[1];
  const float* qb = (const float*)d_in[2];
  const float* kw = (const float*)d_in[3];
  const float* vw = (const float*)d_in[4];
  const float* vb = (const float*)d_in[5];
  const float* ow = (const float*)d_in[6];
  const float* ob = (const float*)d_in[7];
  float* out = (float*)d_out;

  char* ws = (char*)d_ws;
  u16*   xb   = (u16*)(ws);                  // 12,779,520 B (MPAD*768*2)
  u16*   wqkv = (u16*)(ws + 12779520);       //  3,538,944
  u16*   wo   = (u16*)(ws + 16318464);       //  1,179,648
  float* bq   = (float*)(ws + 17498112);     //      9,216
  u16*   qkv  = (u16*)(ws + 17507328);       // 38,338,560 (MPAD*2304*2)
  u16*   Ql   = (u16*)(ws + 55845888);       // 12,779,520 (96*1040*64*2)
  u16*   Kl   = (u16*)(ws + 68625408);       // 12,976,128 (96*1056*64*2)
  u16*   Vt   = (u16*)(ws + 81601536);       // 12,976,128 (96*64*1056*2)
  u16*   Ao   = xb;                          // alias: xb dead after GEMM1; pad rows stay 0

  conv_x<<<6240, 256, 0, stream>>>(x, xb);
  conv_w<<<2304, 256, 0, stream>>>(qw, kw, vw, ow, qb, vb, wqkv, wo, bq);
  gemm_bt<0><<<dim3(65, 18), 256, 0, stream>>>(xb, wqkv, qkv, nullptr, bq, NQKV, DIM, MPAD);
  rope_qk<<<12672, 256, 0, stream>>>(qkv, Ql, Kl);
  v_trans<<<3168, 256, 0, stream>>>(qkv, Vt);
  attn_k<<<dim3(96, 17), 256, 0, stream>>>(Ql, Kl, Vt, Ao);
  gemm_bt<1><<<dim3(65, 6), 256, 0, stream>>>(Ao, wo, nullptr, out, ob, DIM, DIM, NB * SEQ);
}

// Round 2
// 187.139 us; speedup vs baseline: 1.7041x; 1.7041x over previous
//
#include <hip/hip_runtime.h>

typedef unsigned short u16;
typedef unsigned int   u32;
typedef __attribute__((ext_vector_type(4))) short s4;
typedef __attribute__((ext_vector_type(8))) short s8;
typedef __attribute__((ext_vector_type(4))) float f4;
typedef __attribute__((ext_vector_type(16))) float f16v;

#define NB   8
#define SEQ  1025
#define DIM  768
#define NH   12
#define HD   64
#define MPAD 8320      // 65*128 padded rows of B*SEQ=8200
#define MV   8200      // valid rows
#define SQP  1040      // Q rows padded per (b,h)
#define SKP  1088      // K/V rows padded per (b,h): 17*64
#define NQKV 2304
#define BHT  96        // B*H
// hd^-0.5 * log2(e) folded into Q (softmax uses exp2)
#define QSCALE 0.1803368801111204f

__device__ __forceinline__ u16 f2bf(float f) {
  u32 u = __builtin_bit_cast(u32, f);
  u += 0x7fffu + ((u >> 16) & 1u);
  return (u16)(u >> 16);
}
__device__ __forceinline__ float bf2f(u16 h) {
  return __builtin_bit_cast(float, ((u32)h) << 16);
}
__device__ __forceinline__ float exp2f_(float x) {
#if __has_builtin(__builtin_amdgcn_exp2f)
  return __builtin_amdgcn_exp2f(x);
#else
  return exp2f(x);
#endif
}
__device__ __forceinline__ u32 cvtpk(float a, float b) {
  u32 r;
  asm("v_cvt_pk_bf16_f32 %0, %1, %2" : "=v"(r) : "v"(a), "v"(b));
  return r;
}

typedef const __attribute__((address_space(1))) void cas1v;
typedef __attribute__((address_space(3))) void as3v;
__device__ __forceinline__ void gload16(const void* g, void* l) {
  __builtin_amdgcn_global_load_lds((cas1v*)g, (as3v*)l, 16, 0, 0);
}

#define MFMA16(a, b, c) __builtin_amdgcn_mfma_f32_16x16x32_bf16(a, b, c, 0, 0, 0)
#define MFMA32(a, b, c) __builtin_amdgcn_mfma_f32_32x32x16_bf16(a, b, c, 0, 0, 0)

// ---------------- convert x (f32 -> bf16, zero-pad rows >= 8200) ----------------
__global__ void conv_x(const float* __restrict__ x, u16* __restrict__ xb) {
  int i = blockIdx.x * 256 + threadIdx.x;
  int e = i * 4;
  int row = e / DIM;
  s4 o;
  if (row < MV) {
    float4 v = *(const float4*)(x + e);
    o[0] = (short)f2bf(v.x); o[1] = (short)f2bf(v.y);
    o[2] = (short)f2bf(v.z); o[3] = (short)f2bf(v.w);
  } else {
    o = (s4){0, 0, 0, 0};
  }
  *(s4*)(xb + e) = o;
}

// ---------------- convert weights + build fused qkv bias ----------------
__global__ void conv_w(const float* __restrict__ qw, const float* __restrict__ kw,
                       const float* __restrict__ vw, const float* __restrict__ ow,
                       const float* __restrict__ qb, const float* __restrict__ vb,
                       u16* __restrict__ wqkv, u16* __restrict__ wo, float* __restrict__ biasq) {
  int i = blockIdx.x * 256 + threadIdx.x;
  wqkv[i]           = f2bf(qw[i]);
  wqkv[i + 589824]  = f2bf(kw[i]);
  wqkv[i + 1179648] = f2bf(vw[i]);
  wo[i]             = f2bf(ow[i]);
  if (i < NQKV) biasq[i] = (i < 768) ? qb[i] : (i < 1536 ? 0.f : vb[i - 1536]);
}

// ---------------- bf16 GEMM: C[m][n] = sum_k A[m][k]*B[n][k] + bias[n] ----------------
template <int OUTF32>
__global__ __launch_bounds__(256) void gemm_bt(const u16* __restrict__ A, const u16* __restrict__ Bm,
                                               u16* __restrict__ Cb, float* __restrict__ Cf,
                                               const float* __restrict__ bias,
                                               int N, int K, int Mvalid) {
  __shared__ u16 As[128 * 32];
  __shared__ u16 Bs[128 * 32];
  int tid = threadIdx.x;
  int lane = tid & 63, wave = tid >> 6;
  int g = lane >> 4, c16 = lane & 15;
  int m0 = blockIdx.x * 128, n0 = blockIdx.y * 128;
  int wm = wave >> 1, wn = wave & 1;
  f4 acc[4][4] = {};

  int ldrow = wave * 16 + (lane >> 2);
  int ldk = (lane & 3) * 8;
  const u16* Asrc = A + (size_t)(m0 + ldrow) * K + ldk;
  const u16* Bsrc = Bm + (size_t)(n0 + ldrow) * K + ldk;
  u16* AsW = As + wave * 512;
  u16* BsW = Bs + wave * 512;

  for (int k0 = 0; k0 < K; k0 += 32) {
    __syncthreads();
    gload16(Asrc + k0,          AsW);
    gload16(Asrc + 64 * K + k0, AsW + 2048);
    gload16(Bsrc + k0,          BsW);
    gload16(Bsrc + 64 * K + k0, BsW + 2048);
    __syncthreads();
    s8 af[4], bf[4];
#pragma unroll
    for (int i = 0; i < 4; i++) {
      af[i] = *(const s8*)(As + (wm * 64 + i * 16 + c16) * 32 + g * 8);
      bf[i] = *(const s8*)(Bs + (wn * 64 + i * 16 + c16) * 32 + g * 8);
    }
#pragma unroll
    for (int i = 0; i < 4; i++)
#pragma unroll
      for (int j = 0; j < 4; j++)
        acc[i][j] = MFMA16(af[i], bf[j], acc[i][j]);
  }

#pragma unroll
  for (int i = 0; i < 4; i++)
#pragma unroll
    for (int j = 0; j < 4; j++) {
      int m = m0 + wm * 64 + i * 16 + g * 4;
      int n = n0 + wn * 64 + j * 16 + c16;
      float bv = bias ? bias[n] : 0.f;
#pragma unroll
      for (int r = 0; r < 4; r++) {
        if (m + r < Mvalid) {
          float v = acc[i][j][r] + bv;
          if (OUTF32) Cf[(size_t)(m + r) * N + n] = v;
          else        Cb[(size_t)(m + r) * N + n] = f2bf(v);
        }
      }
    }
}

// ---------------- RoPE for Q,K + relayout to padded per-(b,h) buffers ----------------
__global__ void rope_qk(const u16* __restrict__ qkv, u16* __restrict__ Ql, u16* __restrict__ Kl) {
  int t = blockIdx.x * 256 + threadIdx.x;        // 96*1088*32 threads
  int j = t & 31;
  int rem = t >> 5;
  int s = rem % SKP;
  int bh = rem / SKP;
  if (bh >= BHT) return;
  int b = bh / NH, h = bh % NH;
  size_t qoff = ((size_t)(bh * SQP + s)) * HD + 2 * j;
  size_t koff = ((size_t)(bh * SKP + s)) * HD + 2 * j;
  if (s >= SEQ) {
    *(u32*)(Kl + koff) = 0;
    if (s < SQP) *(u32*)(Ql + qoff) = 0;
    return;
  }
  size_t rowoff = ((size_t)(b * SEQ + s)) * NQKV + h * HD + 2 * j;
  u32 qp = *(const u32*)(qkv + rowoff);
  u32 kp = *(const u32*)(qkv + rowoff + DIM);
  float q0 = bf2f((u16)qp), q1 = bf2f((u16)(qp >> 16));
  float k0 = bf2f((u16)kp), k1 = bf2f((u16)(kp >> 16));
  float cs = 1.f, sn = 0.f;
  if (s > 0) {                                   // num_prefix_tokens = 1
    int tok = s - 1;
    int pos = (j < 16) ? (tok >> 5) : (tok & 31);
    int f = j & 15;
    float ang = (float)pos * __expf((float)f * -0.28782313662425572f); // 100^(-f/16)
    __sincosf(ang, &sn, &cs);
  }
  float q0r = q0 * cs - q1 * sn, q1r = q1 * cs + q0 * sn;
  float k0r = k0 * cs - k1 * sn, k1r = k1 * cs + k0 * sn;
  *(u32*)(Ql + qoff) = (u32)f2bf(q0r * QSCALE) | ((u32)f2bf(q1r * QSCALE) << 16);
  *(u32*)(Kl + koff) = (u32)f2bf(k0r) | ((u32)f2bf(k1r) << 16);
}

// ---------------- V transpose: qkv[.,1536+h*64+d] -> Vt[(bh*64+d)*SKP + s] ----------------
__global__ void v_trans(const u16* __restrict__ qkv, u16* __restrict__ Vt) {
  __shared__ u16 tile[32][72];
  int bh = blockIdx.x / 34, st = blockIdx.x % 34;
  int b = bh / NH, h = bh % NH;
  int s0 = st * 32;
  int tid = threadIdx.x;
  {
    int sl = tid >> 3, c8 = (tid & 7) * 8;
    int s = s0 + sl;
    s8 v = (s8){0, 0, 0, 0, 0, 0, 0, 0};
    if (s < SEQ) v = *(const s8*)(qkv + ((size_t)(b * SEQ + s)) * NQKV + 1536 + h * HD + c8);
    *(s8*)&tile[sl][c8] = v;
  }
  __syncthreads();
  {
    int d = tid >> 2, sc = (tid & 3) * 8;
    s8 o;
#pragma unroll
    for (int u = 0; u < 8; u++) o[u] = (short)tile[sc + u][d];
    *(s8*)(Vt + ((size_t)(bh * HD + d)) * SKP + s0 + sc) = o;
  }
}

// ---------------- flash attention: 4 waves x 32 q-rows, KVBLK=64, LDS-staged K/V ----------------
__global__ __launch_bounds__(256) void attn_k(const u16* __restrict__ Q, const u16* __restrict__ K,
                                              const u16* __restrict__ V, u16* __restrict__ Ao) {
  __shared__ u16 lds[2][2][64 * 64];   // [buf][K/V][64 rows x 64 cols bf16] = 32 KiB
  int bh = blockIdx.x;
  int tid = threadIdx.x;
  int wave = tid >> 6, lane = tid & 63;
  int q32 = lane & 31, h = lane >> 5;
  int b = bh / NH, hh = bh % NH;
  int qb = blockIdx.y * 128 + wave * 32;
  if (qb > SEQ - 32) qb = SEQ - 32;    // 993: tail waves recompute rows (identical writes)
  const u16* Qb = Q + (size_t)bh * SQP * HD;
  const u16* Kb = K + (size_t)bh * SKP * HD;
  const u16* Vb = V + (size_t)bh * HD * SKP;

  // Q fragments: qf[t] = Q[qb+q32][16t + 8h .. +8)
  s8 qf[4];
#pragma unroll
  for (int t = 0; t < 4; t++)
    qf[t] = *(const s8*)(Qb + (size_t)(qb + q32) * HD + 16 * t + 8 * h);

  f16v o0 = {}, o1 = {};
  float mrun = -3e38f, lrun = 0.f;
  int swz = (q32 & 7) << 4;

  // stage: K,V 64x64 bf16 tiles; inverse-swizzled global source, linear LDS dest (rule #21)
  auto stage = [&](int buf, int kv0) {
#pragma unroll
    for (int i = 0; i < 2; i++) {
      int sb = i * 4096 + tid * 16;
      int row = sb >> 7;
      int ch = (sb >> 4) & 7;
      int so = (ch ^ (row & 7)) * 8;   // elements
      u16* kd = &lds[buf][0][(i * 4096 + wave * 1024) >> 1];
      u16* vd = &lds[buf][1][(i * 4096 + wave * 1024) >> 1];
      gload16(Kb + (size_t)(kv0 + row) * HD + so, kd);
      gload16(Vb + (size_t)row * SKP + kv0 + so, vd);
    }
  };

  stage(0, 0);
  __syncthreads();

  for (int c = 0; c < 17; c++) {
    int buf = c & 1;
    if (c < 16) stage(buf ^ 1, (c + 1) * 64);
    const char* Ks = (const char*)&lds[buf][0][0];
    const char* Vs = (const char*)&lds[buf][1][0];

    // QK^T swapped: st[k][q], A = K rows (row = q32), B = Q (col = q32)
    f16v st0 = {}, st1 = {};
#pragma unroll
    for (int t = 0; t < 4; t++) {
      int off = (32 * t + 16 * h) ^ swz;
      s8 a0 = *(const s8*)(Ks + q32 * 128 + off);
      s8 a1 = *(const s8*)(Ks + (32 + q32) * 128 + off);
      st0 = MFMA32(a0, qf[t], st0);
      st1 = MFMA32(a1, qf[t], st1);
    }

    if (c == 16) {                     // tail: only kv=1024 (reg0,h=0,tile0) valid
      st0[0] = h ? -3e38f : st0[0];
#pragma unroll
      for (int r = 1; r < 16; r++) st0[r] = -3e38f;
#pragma unroll
      for (int r = 0; r < 16; r++) st1[r] = -3e38f;
    }

    float pmax = -3e38f;
#pragma unroll
    for (int r = 0; r < 16; r++) pmax = fmaxf(pmax, fmaxf(st0[r], st1[r]));
    pmax = fmaxf(pmax, __shfl_xor(pmax, 32));

    if (!__all(pmax <= mrun + 11.5f)) {      // defer-max (T13), exp2 domain
      float mnew = fmaxf(mrun, pmax);
      float cf = exp2f_(mrun - mnew);
      lrun *= cf;
      mrun = mnew;
#pragma unroll
      for (int r = 0; r < 16; r++) {
        float c2 = __shfl(cf, (r & 3) + 8 * (r >> 2) + 4 * h);
        o0[r] *= c2;
        o1[r] *= c2;
      }
    }

    float ps = 0.f;
#pragma unroll
    for (int r = 0; r < 16; r++) {
      st0[r] = exp2f_(st0[r] - mrun);
      st1[r] = exp2f_(st1[r] - mrun);
      ps += st0[r] + st1[r];
    }
    ps += __shfl_xor(ps, 32);
    lrun += ps;

    // PV: A = P (row = q32, slots f(h,j) = 4h+(j&3)+8(j>>2)), B = V^T slices with same map
#pragma unroll
    for (int s = 0; s < 4; s++) {
      union { s8 v; u32 w[4]; } pa;
#pragma unroll
      for (int i = 0; i < 4; i++) {
        float plo = (s < 2) ? st0[8 * (s & 1) + 2 * i]     : st1[8 * (s & 1) + 2 * i];
        float phi = (s < 2) ? st0[8 * (s & 1) + 2 * i + 1] : st1[8 * (s & 1) + 2 * i + 1];
        pa.w[i] = cvtpk(plo, phi);
      }
      int ob = (32 * s + 8 * h) ^ swz;
      const char* v0 = Vs + q32 * 128;
      const char* v1 = Vs + (32 + q32) * 128;
      s4 lo, hi;
      lo = *(const s4*)(v0 + ob); hi = *(const s4*)(v0 + (ob ^ 16));
      s8 vf0 = (s8){lo[0], lo[1], lo[2], lo[3], hi[0], hi[1], hi[2], hi[3]};
      lo = *(const s4*)(v1 + ob); hi = *(const s4*)(v1 + (ob ^ 16));
      s8 vf1 = (s8){lo[0], lo[1], lo[2], lo[3], hi[0], hi[1], hi[2], hi[3]};
      o0 = MFMA32(pa.v, vf0, o0);
      o1 = MFMA32(pa.v, vf1, o1);
    }
    __syncthreads();
  }

  float rl = 1.0f / lrun;
#pragma unroll
  for (int r = 0; r < 16; r++) {
    int cr = (r & 3) + 8 * (r >> 2) + 4 * h;
    float sc = __shfl(rl, cr);
    u16* dst = Ao + (size_t)(b * SEQ + qb + cr) * DIM + hh * HD;
    dst[q32]      = f2bf(o0[r] * sc);
    dst[32 + q32] = f2bf(o1[r] * sc);
  }
}

extern "C" void kernel_launch(void* const* d_in, const int* in_sizes, int n_in,
                              void* d_out, int out_size, void* d_ws, size_t ws_size,
                              hipStream_t stream) {
  const float* x  = (const float*)d_in[0];
  const float* qw = (const float*)d_in[1];
  const float* qb = (const float*)d_in[2];
  const float* kw = (const float*)d_in[3];
  const float* vw = (const float*)d_in[4];
  const float* vb = (const float*)d_in[5];
  const float* ow = (const float*)d_in[6];
  const float* ob = (const float*)d_in[7];
  float* out = (float*)d_out;

  char* ws = (char*)d_ws;
  u16*   xb   = (u16*)(ws);                  // 12,779,520 B (MPAD*768*2)
  u16*   wqkv = (u16*)(ws + 12779520);       //  3,538,944
  u16*   wo   = (u16*)(ws + 16318464);       //  1,179,648
  float* bq   = (float*)(ws + 17498112);     //      9,216
  u16*   qkv  = (u16*)(ws + 17507328);       // 37,785,600 (8200*2304*2)
  u16*   Ql   = (u16*)(ws + 55292928);       // 12,779,520 (96*1040*64*2)
  u16*   Kl   = (u16*)(ws + 68072448);       // 13,369,344 (96*1088*64*2)
  u16*   Vt   = (u16*)(ws + 81441792);       // 13,369,344 (96*64*1088*2)
  u16*   Ao   = xb;                          // alias: xb dead after GEMM1; pad rows stay 0

  conv_x<<<6240, 256, 0, stream>>>(x, xb);
  conv_w<<<2304, 256, 0, stream>>>(qw, kw, vw, ow, qb, vb, wqkv, wo, bq);
  gemm_bt<0><<<dim3(65, 18), 256, 0, stream>>>(xb, wqkv, qkv, nullptr, bq, NQKV, DIM, MV);
  rope_qk<<<13056, 256, 0, stream>>>(qkv, Ql, Kl);
  v_trans<<<3264, 256, 0, stream>>>(qkv, Vt);
  attn_k<<<dim3(96, 9), 256, 0, stream>>>(Ql, Kl, Vt, Ao);
  gemm_bt<1><<<dim3(65, 6), 256, 0, stream>>>(Ao, wo, nullptr, out, ob, DIM, DIM, MV);
}

// Round 3
// 169.175 us; speedup vs baseline: 1.8851x; 1.1062x over previous
//
#include <hip/hip_runtime.h>

typedef unsigned short u16;
typedef unsigned int   u32;
typedef __attribute__((ext_vector_type(4))) short s4;
typedef __attribute__((ext_vector_type(8))) short s8;
typedef __attribute__((ext_vector_type(4))) float f4;
typedef __attribute__((ext_vector_type(16))) float f16v;

#define NB   8
#define SEQ  1025
#define DIM  768
#define NH   12
#define HD   64
#define MPAD 8320      // 65*128 padded rows of B*SEQ=8200
#define MV   8200      // valid rows
#define SQP  1040      // Q rows padded per (b,h)
#define SKP  1088      // K/V rows padded per (b,h): 17*64
#define NQKV 2304
#define BHT  96        // B*H
// hd^-0.5 * log2(e) folded into Q (softmax uses exp2)
#define QSCALE 0.1803368801111204f

__device__ __forceinline__ u16 f2bf(float f) {
  u32 u = __builtin_bit_cast(u32, f);
  u += 0x7fffu + ((u >> 16) & 1u);
  return (u16)(u >> 16);
}
__device__ __forceinline__ float bf2f(u16 h) {
  return __builtin_bit_cast(float, ((u32)h) << 16);
}
__device__ __forceinline__ float exp2f_(float x) {
#if __has_builtin(__builtin_amdgcn_exp2f)
  return __builtin_amdgcn_exp2f(x);
#else
  return exp2f(x);
#endif
}
__device__ __forceinline__ u32 cvtpk(float a, float b) {
  u32 r;
  asm("v_cvt_pk_bf16_f32 %0, %1, %2" : "=v"(r) : "v"(a), "v"(b));
  return r;
}

typedef const __attribute__((address_space(1))) void cas1v;
typedef __attribute__((address_space(3))) void as3v;
__device__ __forceinline__ void gload16(const void* g, void* l) {
  __builtin_amdgcn_global_load_lds((cas1v*)g, (as3v*)l, 16, 0, 0);
}

#define MFMA16(a, b, c) __builtin_amdgcn_mfma_f32_16x16x32_bf16(a, b, c, 0, 0, 0)
#define MFMA32(a, b, c) __builtin_amdgcn_mfma_f32_32x32x16_bf16(a, b, c, 0, 0, 0)

// ---------------- convert x (f32 -> bf16, zero-pad rows >= 8200) ----------------
__global__ void conv_x(const float* __restrict__ x, u16* __restrict__ xb) {
  int i = blockIdx.x * 256 + threadIdx.x;
  int e = i * 4;
  int row = e / DIM;
  s4 o;
  if (row < MV) {
    float4 v = *(const float4*)(x + e);
    o[0] = (short)f2bf(v.x); o[1] = (short)f2bf(v.y);
    o[2] = (short)f2bf(v.z); o[3] = (short)f2bf(v.w);
  } else {
    o = (s4){0, 0, 0, 0};
  }
  *(s4*)(xb + e) = o;
}

// ---------------- convert weights + build fused qkv bias ----------------
__global__ void conv_w(const float* __restrict__ qw, const float* __restrict__ kw,
                       const float* __restrict__ vw, const float* __restrict__ ow,
                       const float* __restrict__ qb, const float* __restrict__ vb,
                       u16* __restrict__ wqkv, u16* __restrict__ wo, float* __restrict__ biasq) {
  int i = blockIdx.x * 256 + threadIdx.x;
  wqkv[i]           = f2bf(qw[i]);
  wqkv[i + 589824]  = f2bf(kw[i]);
  wqkv[i + 1179648] = f2bf(vw[i]);
  wo[i]             = f2bf(ow[i]);
  if (i < NQKV) biasq[i] = (i < 768) ? qb[i] : (i < 1536 ? 0.f : vb[i - 1536]);
}

// ---------------- bf16 GEMM, 128x128 tile, dbuf 2-phase, XCD-swizzled grid ----------------
// MODE 1: f32 C + bias. MODE 2: route columns to Ql/Kl (padded per-(b,h)) and Vr.
template <int MODE>
__global__ __launch_bounds__(256) void gemm_bt(const u16* __restrict__ A, const u16* __restrict__ Bm,
                                               float* __restrict__ Cf, const float* __restrict__ bias,
                                               u16* __restrict__ Ql, u16* __restrict__ Kl,
                                               u16* __restrict__ Vr,
                                               int N, int K, int Mvalid, int nnt) {
  __shared__ u16 As[2][128 * 32];
  __shared__ u16 Bs[2][128 * 32];
  int tid = threadIdx.x;
  int lane = tid & 63, wave = tid >> 6;
  int g = lane >> 4, c16 = lane & 15;
  // bijective XCD swizzle (m204): contiguous wgid chunk per XCD, n fastest -> A-panel L2 reuse
  int nwg = gridDim.x, orig = blockIdx.x;
  int qd = nwg >> 3, rm = nwg & 7, xcd = orig & 7;
  int wgid = (xcd < rm ? xcd * (qd + 1) : rm * (qd + 1) + (xcd - rm) * qd) + (orig >> 3);
  int m0 = (wgid / nnt) * 128, n0 = (wgid % nnt) * 128;
  int wm = wave >> 1, wn = wave & 1;
  f4 acc[4][4] = {};

  int ldrow = wave * 16 + (lane >> 2);
  int ldk = (lane & 3) * 8;
  const u16* Asrc = A + (size_t)(m0 + ldrow) * K + ldk;
  const u16* Bsrc = Bm + (size_t)(n0 + ldrow) * K + ldk;

  auto stage = [&](int buf, int k0) {
    u16* aw = &As[buf][wave * 512];
    u16* bw = &Bs[buf][wave * 512];
    gload16(Asrc + k0, aw);
    gload16(Asrc + 64 * K + k0, aw + 2048);
    gload16(Bsrc + k0, bw);
    gload16(Bsrc + 64 * K + k0, bw + 2048);
  };

  stage(0, 0);
  __syncthreads();                       // drain tile 0
  int nk = K >> 5;
  for (int t = 0; t < nk; t++) {
    int buf = t & 1;
    if (t + 1 < nk) stage(buf ^ 1, (t + 1) << 5);   // issue next-tile loads first
    s8 af[4], bf[4];
#pragma unroll
    for (int i = 0; i < 4; i++) {
      af[i] = *(const s8*)(&As[buf][(wm * 64 + i * 16 + c16) * 32 + g * 8]);
      bf[i] = *(const s8*)(&Bs[buf][(wn * 64 + i * 16 + c16) * 32 + g * 8]);
    }
    __builtin_amdgcn_s_setprio(1);
#pragma unroll
    for (int i = 0; i < 4; i++)
#pragma unroll
      for (int j = 0; j < 4; j++)
        acc[i][j] = MFMA16(af[i], bf[j], acc[i][j]);
    __builtin_amdgcn_s_setprio(0);
    __syncthreads();                     // drains next-tile gloads + this tile's ds_reads
  }

#pragma unroll
  for (int i = 0; i < 4; i++)
#pragma unroll
    for (int j = 0; j < 4; j++) {
      int n = n0 + wn * 64 + j * 16 + c16;
      float bv = bias[n];
#pragma unroll
      for (int r = 0; r < 4; r++) {
        int m = m0 + wm * 64 + i * 16 + g * 4 + r;
        if (m < Mvalid) {
          float v = acc[i][j][r] + bv;
          if (MODE == 1) {
            Cf[(size_t)m * N + n] = v;
          } else {
            int b = m / 1025, s = m - b * 1025;
            int nh6 = n >> 6, part = nh6 / 12, h = nh6 - part * 12, d = n & 63;
            u16 o = f2bf(v);
            if (part == 0)      Ql[((size_t)((b * NH + h) * SQP + s)) * HD + d] = o;
            else if (part == 1) Kl[((size_t)((b * NH + h) * SKP + s)) * HD + d] = o;
            else                Vr[(size_t)m * DIM + (n - 1536)] = o;
          }
        }
      }
    }
}

// ---------------- RoPE for Q,K in place on padded per-(b,h) buffers ----------------
__global__ void rope_qk(u16* __restrict__ Ql, u16* __restrict__ Kl) {
  int t = blockIdx.x * 256 + threadIdx.x;        // 96*1088*32 threads
  int j = t & 31;
  int rem = t >> 5;
  int s = rem % SKP;
  int bh = rem / SKP;
  if (bh >= BHT) return;
  size_t qoff = ((size_t)(bh * SQP + s)) * HD + 2 * j;
  size_t koff = ((size_t)(bh * SKP + s)) * HD + 2 * j;
  if (s >= SEQ) {                                // zero pad rows
    *(u32*)(Kl + koff) = 0;
    if (s < SQP) *(u32*)(Ql + qoff) = 0;
    return;
  }
  u32 qp = *(const u32*)(Ql + qoff);
  u32 kp = *(const u32*)(Kl + koff);
  float q0 = bf2f((u16)qp), q1 = bf2f((u16)(qp >> 16));
  float k0 = bf2f((u16)kp), k1 = bf2f((u16)(kp >> 16));
  float cs = 1.f, sn = 0.f;
  if (s > 0) {                                   // num_prefix_tokens = 1
    int tok = s - 1;
    int pos = (j < 16) ? (tok >> 5) : (tok & 31);
    int f = j & 15;
    float ang = (float)pos * __expf((float)f * -0.28782313662425572f); // 100^(-f/16)
    __sincosf(ang, &sn, &cs);
  }
  float q0r = q0 * cs - q1 * sn, q1r = q1 * cs + q0 * sn;
  float k0r = k0 * cs - k1 * sn, k1r = k1 * cs + k0 * sn;
  *(u32*)(Ql + qoff) = (u32)f2bf(q0r * QSCALE) | ((u32)f2bf(q1r * QSCALE) << 16);
  *(u32*)(Kl + koff) = (u32)f2bf(k0r) | ((u32)f2bf(k1r) << 16);
}

// ---------------- V transpose: Vr[(b*SEQ+s)*768 + h*64+d] -> Vt[(bh*64+d)*SKP + s] ----------------
__global__ void v_trans(const u16* __restrict__ Vr, u16* __restrict__ Vt) {
  __shared__ u16 tile[32][72];
  int bh = blockIdx.x / 34, st = blockIdx.x % 34;
  int b = bh / NH, h = bh % NH;
  int s0 = st * 32;
  int tid = threadIdx.x;
  {
    int sl = tid >> 3, c8 = (tid & 7) * 8;
    int s = s0 + sl;
    s8 v = (s8){0, 0, 0, 0, 0, 0, 0, 0};
    if (s < SEQ) v = *(const s8*)(Vr + ((size_t)(b * SEQ + s)) * DIM + h * HD + c8);
    *(s8*)&tile[sl][c8] = v;
  }
  __syncthreads();
  {
    int d = tid >> 2, sc = (tid & 3) * 8;
    s8 o;
#pragma unroll
    for (int u = 0; u < 8; u++) o[u] = (short)tile[sc + u][d];
    *(s8*)(Vt + ((size_t)(bh * HD + d)) * SKP + s0 + sc) = o;
  }
}

// ---------------- flash attention: 4 waves x 32 q-rows, KVBLK=64, LDS-staged K/V ----------------
__global__ __launch_bounds__(256) void attn_k(const u16* __restrict__ Q, const u16* __restrict__ K,
                                              const u16* __restrict__ V, u16* __restrict__ Ao) {
  __shared__ u16 lds[2][2][64 * 64];   // [buf][K/V][64 rows x 64 cols bf16] = 32 KiB
  int bh = blockIdx.x;
  int tid = threadIdx.x;
  int wave = tid >> 6, lane = tid & 63;
  int q32 = lane & 31, h = lane >> 5;
  int b = bh / NH, hh = bh % NH;
  int qb = blockIdx.y * 128 + wave * 32;
  if (qb > SEQ - 32) qb = SEQ - 32;    // 993: tail waves recompute rows (identical writes)
  const u16* Qb = Q + (size_t)bh * SQP * HD;
  const u16* Kb = K + (size_t)bh * SKP * HD;
  const u16* Vb = V + (size_t)bh * HD * SKP;

  // Q fragments: qf[t] = Q[qb+q32][16t + 8h .. +8)
  s8 qf[4];
#pragma unroll
  for (int t = 0; t < 4; t++)
    qf[t] = *(const s8*)(Qb + (size_t)(qb + q32) * HD + 16 * t + 8 * h);

  f16v o0 = {}, o1 = {};
  float mrun = -3e38f, lrun = 0.f;
  int swz = (q32 & 7) << 4;

  // stage: K,V 64x64 bf16 tiles; inverse-swizzled global source, linear LDS dest (rule #21)
  auto stage = [&](int buf, int kv0) {
#pragma unroll
    for (int i = 0; i < 2; i++) {
      int sb = i * 4096 + tid * 16;
      int row = sb >> 7;
      int ch = (sb >> 4) & 7;
      int so = (ch ^ (row & 7)) * 8;   // elements
      u16* kd = &lds[buf][0][(i * 4096 + wave * 1024) >> 1];
      u16* vd = &lds[buf][1][(i * 4096 + wave * 1024) >> 1];
      gload16(Kb + (size_t)(kv0 + row) * HD + so, kd);
      gload16(Vb + (size_t)row * SKP + kv0 + so, vd);
    }
  };

  stage(0, 0);
  __syncthreads();

  for (int c = 0; c < 17; c++) {
    int buf = c & 1;
    if (c < 16) stage(buf ^ 1, (c + 1) * 64);
    const char* Ks = (const char*)&lds[buf][0][0];
    const char* Vs = (const char*)&lds[buf][1][0];

    // QK^T swapped: st[k][q], A = K rows (row = q32), B = Q (col = q32)
    f16v st0 = {}, st1 = {};
    __builtin_amdgcn_s_setprio(1);
#pragma unroll
    for (int t = 0; t < 4; t++) {
      int off = (32 * t + 16 * h) ^ swz;
      s8 a0 = *(const s8*)(Ks + q32 * 128 + off);
      s8 a1 = *(const s8*)(Ks + (32 + q32) * 128 + off);
      st0 = MFMA32(a0, qf[t], st0);
      st1 = MFMA32(a1, qf[t], st1);
    }
    __builtin_amdgcn_s_setprio(0);

    if (c == 16) {                     // tail: only kv=1024 (reg0,h=0,tile0) valid
      st0[0] = h ? -3e38f : st0[0];
#pragma unroll
      for (int r = 1; r < 16; r++) st0[r] = -3e38f;
#pragma unroll
      for (int r = 0; r < 16; r++) st1[r] = -3e38f;
    }

    float pmax = -3e38f;
#pragma unroll
    for (int r = 0; r < 16; r++) pmax = fmaxf(pmax, fmaxf(st0[r], st1[r]));
    pmax = fmaxf(pmax, __shfl_xor(pmax, 32));

    if (!__all(pmax <= mrun + 11.5f)) {      // defer-max (T13), exp2 domain
      float mnew = fmaxf(mrun, pmax);
      float cf = exp2f_(mrun - mnew);
      lrun *= cf;
      mrun = mnew;
#pragma unroll
      for (int r = 0; r < 16; r++) {
        float c2 = __shfl(cf, (r & 3) + 8 * (r >> 2) + 4 * h);
        o0[r] *= c2;
        o1[r] *= c2;
      }
    }

    float ps = 0.f;
#pragma unroll
    for (int r = 0; r < 16; r++) {
      st0[r] = exp2f_(st0[r] - mrun);
      st1[r] = exp2f_(st1[r] - mrun);
      ps += st0[r] + st1[r];
    }
    ps += __shfl_xor(ps, 32);
    lrun += ps;

    // PV: A = P (row = q32, slots f(h,j) = 4h+(j&3)+8(j>>2)), B = V^T slices with same map
    __builtin_amdgcn_s_setprio(1);
#pragma unroll
    for (int s = 0; s < 4; s++) {
      union { s8 v; u32 w[4]; } pa;
#pragma unroll
      for (int i = 0; i < 4; i++) {
        float plo = (s < 2) ? st0[8 * (s & 1) + 2 * i]     : st1[8 * (s & 1) + 2 * i];
        float phi = (s < 2) ? st0[8 * (s & 1) + 2 * i + 1] : st1[8 * (s & 1) + 2 * i + 1];
        pa.w[i] = cvtpk(plo, phi);
      }
      int ob = (32 * s + 8 * h) ^ swz;
      const char* v0 = Vs + q32 * 128;
      const char* v1 = Vs + (32 + q32) * 128;
      s4 lo, hi;
      lo = *(const s4*)(v0 + ob); hi = *(const s4*)(v0 + (ob ^ 16));
      s8 vf0 = (s8){lo[0], lo[1], lo[2], lo[3], hi[0], hi[1], hi[2], hi[3]};
      lo = *(const s4*)(v1 + ob); hi = *(const s4*)(v1 + (ob ^ 16));
      s8 vf1 = (s8){lo[0], lo[1], lo[2], lo[3], hi[0], hi[1], hi[2], hi[3]};
      o0 = MFMA32(pa.v, vf0, o0);
      o1 = MFMA32(pa.v, vf1, o1);
    }
    __builtin_amdgcn_s_setprio(0);
    __syncthreads();
  }

  float rl = 1.0f / lrun;
#pragma unroll
  for (int r = 0; r < 16; r++) {
    int cr = (r & 3) + 8 * (r >> 2) + 4 * h;
    float sc = __shfl(rl, cr);
    u16* dst = Ao + (size_t)(b * SEQ + qb + cr) * DIM + hh * HD;
    dst[q32]      = f2bf(o0[r] * sc);
    dst[32 + q32] = f2bf(o1[r] * sc);
  }
}

extern "C" void kernel_launch(void* const* d_in, const int* in_sizes, int n_in,
                              void* d_out, int out_size, void* d_ws, size_t ws_size,
                              hipStream_t stream) {
  const float* x  = (const float*)d_in[0];
  const float* qw = (const float*)d_in[1];
  const float* qb = (const float*)d_in[2];
  const float* kw = (const float*)d_in[3];
  const float* vw = (const float*)d_in[4];
  const float* vb = (const float*)d_in[5];
  const float* ow = (const float*)d_in[6];
  const float* ob = (const float*)d_in[7];
  float* out = (float*)d_out;

  char* ws = (char*)d_ws;
  u16*   xb   = (u16*)(ws);                  // 12,779,520 B (MPAD*768*2)
  u16*   wqkv = (u16*)(ws + 12779520);       //  3,538,944
  u16*   wo   = (u16*)(ws + 16318464);       //  1,179,648
  float* bq   = (float*)(ws + 17498112);     //      9,216
  u16*   Vr   = (u16*)(ws + 17507328);       // 12,595,200 (8200*768*2)
  u16*   Ql   = (u16*)(ws + 30102528);       // 12,779,520 (96*1040*64*2)
  u16*   Kl   = (u16*)(ws + 42882048);       // 13,369,344 (96*1088*64*2)
  u16*   Vt   = (u16*)(ws + 56251392);       // 13,369,344 (96*64*1088*2)
  u16*   Ao   = xb;                          // alias: xb dead after GEMM1; pad rows stay 0

  conv_x<<<6240, 256, 0, stream>>>(x, xb);
  conv_w<<<2304, 256, 0, stream>>>(qw, kw, vw, ow, qb, vb, wqkv, wo, bq);
  gemm_bt<2><<<1170, 256, 0, stream>>>(xb, wqkv, nullptr, bq, Ql, Kl, Vr, NQKV, DIM, MV, 18);
  rope_qk<<<13056, 256, 0, stream>>>(Ql, Kl);
  v_trans<<<3264, 256, 0, stream>>>(Vr, Vt);
  attn_k<<<dim3(96, 9), 256, 0, stream>>>(Ql, Kl, Vt, Ao);
  gemm_bt<1><<<390, 256, 0, stream>>>(Ao, wo, out, ob, nullptr, nullptr, nullptr, DIM, DIM, MV, 6);
}